// Round 2
// baseline (76.277 us; speedup 1.0000x reference)
//
#include <hip/hip_runtime.h>

// OTAM cumulative-distance matching, fused forward+transposed DP in one pass.
// similarity: [2048, 128, 16, 16] f32 ; out: [2048, 128] f32
//
// DP recurrence (W = 18 padded support axis, lambda = 0.1):
//   cum[l,m] = d[l,m] - L*logsumexp(-cum[l-1,m-1]/L, -cum[l,m-1]/L,
//                                   (m==1||m==17) ? -cum[l-1,m]/L : -inf)
// DP1 runs row-major over D (consumes D rows); DP2 (the DP on D^T) runs
// column-major, which also consumes D rows -> single streaming read of the
// 16x16 tile serves both DPs. Interior columns of DP2 have no intra-column
// dependency, so column-major order is legal (boundary columns m=1, m=17
// use the already-updated C[l-1]).

#define K2   14.4269504088896340736f   // 1/(lambda*ln2) = log2(e)/lambda, lambda=0.1
#define LL2  0.069314718055994530942f  // lambda*ln(2)

// softmin(a,b) = -L*ln(e^{-a/L} + e^{-b/L}) = min - L*ln(1 + e^{-|a-b|/L})
__device__ __forceinline__ float softmin2(float a, float b) {
    float mn = fminf(a, b);
    float t  = __builtin_amdgcn_exp2f(-K2 * fabsf(a - b));
    return mn - LL2 * __builtin_amdgcn_logf(1.0f + t);  // logf == v_log_f32 == log2
}

__device__ __forceinline__ float softmin3(float a, float b, float c) {
    float mn = fminf(fminf(a, b), c);   // v_min3_f32
    float s = __builtin_amdgcn_exp2f(-K2 * (a - mn))
            + __builtin_amdgcn_exp2f(-K2 * (b - mn))
            + __builtin_amdgcn_exp2f(-K2 * (c - mn));
    return mn - LL2 * __builtin_amdgcn_logf(s);
}

__device__ __forceinline__ void load_row(const float* __restrict__ p, float* dr) {
    const float4* rp = reinterpret_cast<const float4*>(p);
    float4 v0 = rp[0], v1 = rp[1], v2 = rp[2], v3 = rp[3];
    dr[0]  = 1.0f - v0.x; dr[1]  = 1.0f - v0.y; dr[2]  = 1.0f - v0.z; dr[3]  = 1.0f - v0.w;
    dr[4]  = 1.0f - v1.x; dr[5]  = 1.0f - v1.y; dr[6]  = 1.0f - v1.z; dr[7]  = 1.0f - v1.w;
    dr[8]  = 1.0f - v2.x; dr[9]  = 1.0f - v2.y; dr[10] = 1.0f - v2.z; dr[11] = 1.0f - v2.w;
    dr[12] = 1.0f - v3.x; dr[13] = 1.0f - v3.y; dr[14] = 1.0f - v3.z; dr[15] = 1.0f - v3.w;
}

__global__ __launch_bounds__(256)
void otam_fused_kernel(const float* __restrict__ sim, float* __restrict__ out, int npairs) {
    int pair = blockIdx.x * blockDim.x + threadIdx.x;
    if (pair >= npairs) return;
    const float* base = sim + ((size_t)pair << 8);

    float R[18];   // DP1 row state  (cum1[row, 0..17]);  R[0] stays 0
    float C[16];   // DP2 col state  (cum2[0..15, col])
    float dr[16];

    // ---- r = 0: DP1 row 0 is a plain cumsum; DP2 column m=1 (boundary) ----
    load_row(base, dr);
    R[0] = 0.0f;
#pragma unroll
    for (int m = 1; m <= 16; ++m) R[m] = R[m - 1] + dr[m - 1];
    R[17] = R[16];  // pad column, d = 0

    // DP2: column 0 is all zeros. Column m=1 uses d2[l,1] = D[0][l] = dr[l].
    C[0] = dr[0];
#pragma unroll
    for (int l = 1; l < 16; ++l) {
        // diag = cum2[l-1,0] = 0, left = cum2[l,0] = 0, up = cum2[l-1,1] (new)
        C[l] = dr[l] + softmin3(0.0f, 0.0f, C[l - 1]);
    }

    // ---- r = 1..15: DP1 row step r; DP2 column step m=r+1 (interior) ----
    for (int r = 1; r < 16; ++r) {
        load_row(base + (r << 4), dr);

        // DP1 row step (in-place with diag carry)
        float diag = R[0];        // cum1[r-1, 0] = 0
        float oldR = R[1];
        R[1] = dr[0] + softmin3(diag, R[0], oldR);   // m=1 boundary
        diag = oldR;
#pragma unroll
        for (int m = 2; m <= 16; ++m) {
            float o = R[m];
            R[m] = dr[m - 1] + softmin2(diag, R[m - 1]);
            diag = o;
        }
        // m = 17: d = 0, boundary
        R[17] = softmin3(diag, R[16], R[17]);

        // DP2 column step, column m = r+1 in 2..16 (interior, no intra-col dep)
        float diag2 = C[0];       // cum2[0, m-1]
        C[0] = C[0] + dr[0];      // DP2 row 0 cumsum
#pragma unroll
        for (int l = 1; l < 16; ++l) {
            float o = C[l];
            C[l] = dr[l] + softmin2(diag2, o);
            diag2 = o;
        }
    }

    // ---- DP2 final column m = 17: d = 0, boundary ----
    {
        float diag2 = C[0];
        // C[0] += 0 (pad)
#pragma unroll
        for (int l = 1; l < 16; ++l) {
            float o = C[l];
            C[l] = softmin3(diag2, o, C[l - 1]);
            diag2 = o;
        }
    }

    out[pair] = -0.5f * (R[17] + C[15]);
}

extern "C" void kernel_launch(void* const* d_in, const int* in_sizes, int n_in,
                              void* d_out, int out_size, void* d_ws, size_t ws_size,
                              hipStream_t stream) {
    const float* sim = (const float*)d_in[0];
    float* out = (float*)d_out;
    int npairs = in_sizes[0] >> 8;          // (Q*S*16*16)/256
    int block = 256;
    int grid = (npairs + block - 1) / block;
    otam_fused_kernel<<<grid, block, 0, stream>>>(sim, out, npairs);
}